// Round 1
// baseline (223.624 us; speedup 1.0000x reference)
//
#include <hip/hip_runtime.h>

typedef __attribute__((ext_vector_type(8))) __bf16 bf16x8;
typedef __attribute__((ext_vector_type(4))) __bf16 bf16x4;
typedef __attribute__((ext_vector_type(4))) float f32x4;

#define NB 4
#define SEQ 2048
#define HID 768
#define NH 12
#define HD 64

#define MFMA(a,b,c) __builtin_amdgcn_mfma_f32_16x16x32_bf16(a, b, c, 0, 0, 0)

// async global->LDS, 16B per lane. LDS dest must be wave-uniform base + lane*16.
#define GLDS16(g, l) __builtin_amdgcn_global_load_lds( \
    (const __attribute__((address_space(1))) void*)(g), \
    (__attribute__((address_space(3))) void*)(l), 16, 0, 0)

// ---------------------------------------------------------------- convert
__global__ __launch_bounds__(256) void cvt_kernel(
    const float* __restrict__ X, const float* __restrict__ Wq,
    const float* __restrict__ Wk, const float* __restrict__ Wv,
    __bf16* __restrict__ Xb, __bf16* __restrict__ Wb) {
  const long NX = (long)NB * SEQ * HID;   // 6291456
  const long NW = (long)HID * HID;        // 589824
  long idx = (long)blockIdx.x * 256 + threadIdx.x;
  long i8 = idx * 8;
  const float* src;
  __bf16* dst;
  if (i8 < NX) {
    src = X + i8; dst = Xb + i8;
  } else {
    long j = i8 - NX;
    int w = (int)(j / NW);
    long r = j - (long)w * NW;
    src = (w == 0 ? Wq : (w == 1 ? Wk : Wv)) + r;
    dst = Wb + j;
  }
  const float4* s4 = (const float4*)src;
  float4 a = s4[0], b = s4[1];
  bf16x8 v;
  v[0] = (__bf16)a.x; v[1] = (__bf16)a.y; v[2] = (__bf16)a.z; v[3] = (__bf16)a.w;
  v[4] = (__bf16)b.x; v[5] = (__bf16)b.y; v[6] = (__bf16)b.z; v[7] = (__bf16)b.w;
  *(bf16x8*)dst = v;
}

// ---------------------------------------------------------------- QKV GEMM
// C[m,n] = sum_k X[m,k] * W[n,k] + bias[n]   (NT layout)
// 128x128 tile, BK=32, 256 threads (4 waves, 2x2), 16x16x32 MFMA.
// LDS chunk-swizzle: logical 16B chunk (r,c) lives at slot c ^ ((r>>1)&3).
__global__ __launch_bounds__(256) void qkv_kernel(
    const __bf16* __restrict__ Xb, const __bf16* __restrict__ Wb,
    const float* __restrict__ bq, const float* __restrict__ bk,
    const float* __restrict__ bv,
    __bf16* __restrict__ Qb, __bf16* __restrict__ Kb, __bf16* __restrict__ Vt) {
  __shared__ alignas(16) __bf16 As[4096];  // 128 rows x 32 k
  __shared__ alignas(16) __bf16 Bs[4096];  // 128 n-rows x 32 k
  int tid = threadIdx.x, lane = tid & 63, wid = tid >> 6;
  int bidx = blockIdx.x;
  int tm = bidx & 63, tn = bidx >> 6;
  int w = tn / 6;                 // 0=Q 1=K 2=V
  int n0 = (tn % 6) * 128;
  int m0 = tm * 128;
  int wm = wid >> 1, wn = wid & 1;
  int la = lane & 15, lg = lane >> 4;

  // staging: thread t loads swizzle-inverse global chunks so LDS dest is linear
  int r0 = tid >> 2, cs0 = tid & 3;
  int c0 = cs0 ^ ((r0 >> 1) & 3);
  int r1 = r0 + 64;
  int c1 = cs0 ^ ((r1 >> 1) & 3);
  long aoff0 = (long)(m0 + r0) * HID + c0 * 8;
  long aoff1 = (long)(m0 + r1) * HID + c1 * 8;
  long wbase = (long)w * HID * HID;
  long boff0 = wbase + (long)(n0 + r0) * HID + c0 * 8;
  long boff1 = wbase + (long)(n0 + r1) * HID + c1 * 8;

  // fragment read offsets (element units)
  int aoffL[4], boffL[4];
#pragma unroll
  for (int i = 0; i < 4; i++) {
    int r = wm * 64 + i * 16 + la;
    aoffL[i] = r * 32 + ((lg ^ ((r >> 1) & 3)) * 8);
    int rb = wn * 64 + i * 16 + la;
    boffL[i] = rb * 32 + ((lg ^ ((rb >> 1) & 3)) * 8);
  }

  f32x4 acc[4][4] = {};
  for (int kt = 0; kt < 24; kt++) {
    int k0 = kt * 32;
    GLDS16(Xb + aoff0 + k0, As + tid * 8);
    GLDS16(Xb + aoff1 + k0, As + 2048 + tid * 8);
    GLDS16(Wb + boff0 + k0, Bs + tid * 8);
    GLDS16(Wb + boff1 + k0, Bs + 2048 + tid * 8);
    __syncthreads();
    bf16x8 af[4], bfv[4];
#pragma unroll
    for (int i = 0; i < 4; i++) af[i] = *(const bf16x8*)(As + aoffL[i]);
#pragma unroll
    for (int j = 0; j < 4; j++) bfv[j] = *(const bf16x8*)(Bs + boffL[j]);
#pragma unroll
    for (int i = 0; i < 4; i++)
#pragma unroll
      for (int j = 0; j < 4; j++)
        acc[i][j] = MFMA(af[i], bfv[j], acc[i][j]);
    __syncthreads();
  }

  // epilogue: bias add, bf16 convert, write Q/K row-major, V transposed [b,h,d,s]
  const float* bias = (w == 0) ? bq : ((w == 1) ? bk : bv);
#pragma unroll
  for (int j = 0; j < 4; j++) {
    int nc = n0 + wn * 64 + j * 16 + la;  // 0..767
    float bb = bias[nc];
#pragma unroll
    for (int i = 0; i < 4; i++) {
      int mrow0 = m0 + wm * 64 + i * 16 + lg * 4;
      f32x4 v = acc[i][j];
      if (w < 2) {
        __bf16* dst = (w == 0 ? Qb : Kb);
#pragma unroll
        for (int reg = 0; reg < 4; reg++)
          dst[(long)(mrow0 + reg) * HID + nc] = (__bf16)(v[reg] + bb);
      } else {
        int bI = mrow0 >> 11, s = mrow0 & 2047;
        int hh = nc >> 6, d = nc & 63;
        bf16x4 pv;
#pragma unroll
        for (int reg = 0; reg < 4; reg++) pv[reg] = (__bf16)(v[reg] + bb);
        *(bf16x4*)(Vt + ((long)(bI * NH + hh) * HD + d) * SEQ + s) = pv;
      }
    }
  }
}

// ---------------------------------------------------------------- attention
// 1 block = 64 q-rows (4 waves x 16), KV tiles of 64, flash-style online softmax.
// K/V tiles: [64 rows][64 elems] bf16, chunk-swizzle slot = c ^ (r&7).
__global__ __launch_bounds__(256) void attn_kernel(
    const __bf16* __restrict__ Qb, const __bf16* __restrict__ Kb,
    const __bf16* __restrict__ Vt, const float* __restrict__ mask,
    float* __restrict__ out) {
  __shared__ alignas(16) __bf16 Ks[4096];
  __shared__ alignas(16) __bf16 Vs[4096];
  __shared__ alignas(16) __bf16 Ps[4096];  // 4 waves x [16 q][64 k]
  int tid = threadIdx.x, lane = tid & 63, wid = tid >> 6;
  int qt = blockIdx.x, h = blockIdx.y, b = blockIdx.z;
  int la = lane & 15, lg = lane >> 4;

  // Q fragments in registers (A-frag: row = lane&15, k = (lane>>4)*8+i)
  int qrow = qt * 64 + wid * 16 + la;
  const __bf16* qp = Qb + (long)(b * SEQ + qrow) * HID + h * HD + lg * 8;
  bf16x8 qa0 = *(const bf16x8*)qp;
  bf16x8 qa1 = *(const bf16x8*)(qp + 32);

  // staging maps (source pre-swizzled, LDS dest linear)
  int r0 = tid >> 3, cc = (tid & 7) ^ (r0 & 7);
  long kbase = (long)(b * SEQ + r0) * HID + h * HD + cc * 8;
  long vbase = (long)((b * NH + h) * HD + r0) * SEQ + cc * 8;

  // fragment read offsets into Ks/Vs (same formula both)
  int koffL[4][2];
#pragma unroll
  for (int j = 0; j < 4; j++) {
    int r = j * 16 + la;
    koffL[j][0] = r * 64 + (((0 + lg) ^ (r & 7)) * 8);
    koffL[j][1] = r * 64 + (((4 + lg) ^ (r & 7)) * 8);
  }
  int poff0 = wid * 1024 + la * 64 + (((0 + lg) ^ (la & 7)) * 8);
  int poff1 = wid * 1024 + la * 64 + (((4 + lg) ^ (la & 7)) * 8);

  float m_run[4], l_run[4];
  f32x4 acc[4] = {};
#pragma unroll
  for (int r = 0; r < 4; r++) { m_run[r] = -10000.0f; l_run[r] = 0.0f; }
  const float* mrow = mask + b * SEQ;

  for (int t = 0; t < 32; t++) {
    GLDS16(Kb + kbase + (long)t * 64 * HID, Ks + tid * 8);
    GLDS16(Kb + kbase + (long)t * 64 * HID + 32L * HID, Ks + 2048 + tid * 8);
    GLDS16(Vt + vbase + t * 64, Vs + tid * 8);
    GLDS16(Vt + vbase + t * 64 + 32L * SEQ, Vs + 2048 + tid * 8);
    __syncthreads();

    // S = Q K^T  (rows: lane holds rows lg*4+r, col = j*16+la)
    f32x4 s[4];
#pragma unroll
    for (int j = 0; j < 4; j++) {
      bf16x8 k0 = *(const bf16x8*)(Ks + koffL[j][0]);
      bf16x8 k1 = *(const bf16x8*)(Ks + koffL[j][1]);
      f32x4 z = {};
      z = MFMA(qa0, k0, z);
      z = MFMA(qa1, k1, z);
      s[j] = z;
    }
    // scale + mask + per-lane row max
    float mx[4] = {-1e30f, -1e30f, -1e30f, -1e30f};
#pragma unroll
    for (int j = 0; j < 4; j++) {
      float mv = mrow[t * 64 + j * 16 + la];
#pragma unroll
      for (int r = 0; r < 4; r++) {
        float sv = s[j][r] * 0.125f;
        sv = (mv < 0.0f) ? -10000.0f : sv;
        s[j][r] = sv;
        mx[r] = fmaxf(mx[r], sv);
      }
    }
#pragma unroll
    for (int r = 0; r < 4; r++) {
#pragma unroll
      for (int o = 1; o < 16; o <<= 1) mx[r] = fmaxf(mx[r], __shfl_xor(mx[r], o, 16));
    }
    float corr[4], rs[4];
#pragma unroll
    for (int r = 0; r < 4; r++) {
      float mn = fmaxf(m_run[r], mx[r]);
      corr[r] = __expf(m_run[r] - mn);
      m_run[r] = mn;
      rs[r] = 0.0f;
    }
#pragma unroll
    for (int j = 0; j < 4; j++)
#pragma unroll
      for (int r = 0; r < 4; r++) {
        float p = __expf(s[j][r] - m_run[r]);
        s[j][r] = p;
        rs[r] += p;
      }
#pragma unroll
    for (int r = 0; r < 4; r++) {
#pragma unroll
      for (int o = 1; o < 16; o <<= 1) rs[r] += __shfl_xor(rs[r], o, 16);
      l_run[r] = l_run[r] * corr[r] + rs[r];
    }
#pragma unroll
    for (int jo = 0; jo < 4; jo++)
#pragma unroll
      for (int r = 0; r < 4; r++) acc[jo][r] *= corr[r];

    // P -> per-wave LDS (swizzled), wave-synchronous transpose to A-frag layout
#pragma unroll
    for (int j = 0; j < 4; j++)
#pragma unroll
      for (int r = 0; r < 4; r++) {
        int row = lg * 4 + r, col = j * 16 + la;
        Ps[wid * 1024 + row * 64 + (((col >> 3) ^ (row & 7)) * 8) + (col & 7)] =
            (__bf16)s[j][r];
      }
    bf16x8 pa0 = *(const bf16x8*)(Ps + poff0);
    bf16x8 pa1 = *(const bf16x8*)(Ps + poff1);

    // O += P V   (B-frag from Vt rows: B[k=s][col=d])
#pragma unroll
    for (int jo = 0; jo < 4; jo++) {
      bf16x8 v0 = *(const bf16x8*)(Vs + koffL[jo][0]);
      bf16x8 v1 = *(const bf16x8*)(Vs + koffL[jo][1]);
      acc[jo] = MFMA(pa0, v0, acc[jo]);
      acc[jo] = MFMA(pa1, v1, acc[jo]);
    }
    __syncthreads();
  }

  // epilogue: out[b, s, h*64+d] = acc / l
#pragma unroll
  for (int jo = 0; jo < 4; jo++)
#pragma unroll
    for (int r = 0; r < 4; r++) {
      int row = qt * 64 + wid * 16 + lg * 4 + r;
      int d = jo * 16 + la;
      out[(long)(b * SEQ + row) * HID + h * HD + d] = acc[jo][r] / l_run[r];
    }
}

// ---------------------------------------------------------------- launch
extern "C" void kernel_launch(void* const* d_in, const int* in_sizes, int n_in,
                              void* d_out, int out_size, void* d_ws, size_t ws_size,
                              hipStream_t stream) {
  const float* X    = (const float*)d_in[0];
  const float* mask = (const float*)d_in[1];
  const float* Wq   = (const float*)d_in[2];
  const float* bq   = (const float*)d_in[3];
  const float* Wk   = (const float*)d_in[4];
  const float* bk   = (const float*)d_in[5];
  const float* Wv   = (const float*)d_in[6];
  const float* bv   = (const float*)d_in[7];

  __bf16* Xb = (__bf16*)d_ws;            // 6291456
  __bf16* Wb = Xb + 6291456;             // 1769472 (Wq,Wk,Wv)
  __bf16* Qb = Wb + 1769472;             // 6291456
  __bf16* Kb = Qb + 6291456;             // 6291456
  __bf16* Vt = Kb + 6291456;             // 6291456, layout [b][h][d][s]
  float* out = (float*)d_out;

  cvt_kernel<<<dim3(3936), dim3(256), 0, stream>>>(X, Wq, Wk, Wv, Xb, Wb);
  qkv_kernel<<<dim3(1152), dim3(256), 0, stream>>>(Xb, Wb, bq, bk, bv, Qb, Kb, Vt);
  attn_kernel<<<dim3(32, 12, 4), dim3(256), 0, stream>>>(Qb, Kb, Vt, mask, out);
}

// Round 2
// 173.653 us; speedup vs baseline: 1.2878x; 1.2878x over previous
//
#include <hip/hip_runtime.h>

typedef __attribute__((ext_vector_type(8))) __bf16 bf16x8;
typedef __attribute__((ext_vector_type(4))) __bf16 bf16x4;
typedef __attribute__((ext_vector_type(4))) float f32x4;

#define NB 4
#define SEQ 2048
#define HID 768
#define NH 12
#define HD 64

#define MFMA(a,b,c) __builtin_amdgcn_mfma_f32_16x16x32_bf16(a, b, c, 0, 0, 0)

// async global->LDS, 16B per lane. LDS dest must be wave-uniform base + lane*16.
#define GLDS16(g, l) __builtin_amdgcn_global_load_lds( \
    (const __attribute__((address_space(1))) void*)(g), \
    (__attribute__((address_space(3))) void*)(l), 16, 0, 0)

// ---------------------------------------------------------------- convert
__global__ __launch_bounds__(256) void cvt_kernel(
    const float* __restrict__ X, const float* __restrict__ Wq,
    const float* __restrict__ Wk, const float* __restrict__ Wv,
    __bf16* __restrict__ Xb, __bf16* __restrict__ Wb) {
  const long NX = (long)NB * SEQ * HID;   // 6291456
  const long NW = (long)HID * HID;        // 589824
  long idx = (long)blockIdx.x * 256 + threadIdx.x;
  long i8 = idx * 8;
  const float* src;
  __bf16* dst;
  if (i8 < NX) {
    src = X + i8; dst = Xb + i8;
  } else {
    long j = i8 - NX;
    int w = (int)(j / NW);
    long r = j - (long)w * NW;
    src = (w == 0 ? Wq : (w == 1 ? Wk : Wv)) + r;
    dst = Wb + j;
  }
  const float4* s4 = (const float4*)src;
  float4 a = s4[0], b = s4[1];
  bf16x8 v;
  v[0] = (__bf16)a.x; v[1] = (__bf16)a.y; v[2] = (__bf16)a.z; v[3] = (__bf16)a.w;
  v[4] = (__bf16)b.x; v[5] = (__bf16)b.y; v[6] = (__bf16)b.z; v[7] = (__bf16)b.w;
  *(bf16x8*)dst = v;
}

// ---------------------------------------------------------------- QKV GEMM
// C[m,n] = sum_k X[m,k] * W[n,k] + bias[n]   (NT layout)
// 128x128 tile, BK=32, 256 threads (4 waves, 2x2), 16x16x32 MFMA.
// LDS chunk-swizzle: logical 16B chunk (r,c) lives at slot c ^ ((r>>1)&3).
__global__ __launch_bounds__(256) void qkv_kernel(
    const __bf16* __restrict__ Xb, const __bf16* __restrict__ Wb,
    const float* __restrict__ bq, const float* __restrict__ bk,
    const float* __restrict__ bv,
    __bf16* __restrict__ Qb, __bf16* __restrict__ Kb, __bf16* __restrict__ Vt) {
  __shared__ alignas(16) __bf16 As[4096];  // 128 rows x 32 k
  __shared__ alignas(16) __bf16 Bs[4096];  // 128 n-rows x 32 k
  int tid = threadIdx.x, lane = tid & 63, wid = tid >> 6;
  int bidx = blockIdx.x;
  int tm = bidx & 63, tn = bidx >> 6;
  int w = tn / 6;                 // 0=Q 1=K 2=V
  int n0 = (tn % 6) * 128;
  int m0 = tm * 128;
  int wm = wid >> 1, wn = wid & 1;
  int la = lane & 15, lg = lane >> 4;

  // staging: thread t loads swizzle-inverse global chunks so LDS dest is linear
  int r0 = tid >> 2, cs0 = tid & 3;
  int c0 = cs0 ^ ((r0 >> 1) & 3);
  int r1 = r0 + 64;
  int c1 = cs0 ^ ((r1 >> 1) & 3);
  long aoff0 = (long)(m0 + r0) * HID + c0 * 8;
  long aoff1 = (long)(m0 + r1) * HID + c1 * 8;
  long wbase = (long)w * HID * HID;
  long boff0 = wbase + (long)(n0 + r0) * HID + c0 * 8;
  long boff1 = wbase + (long)(n0 + r1) * HID + c1 * 8;

  // fragment read offsets (element units)
  int aoffL[4], boffL[4];
#pragma unroll
  for (int i = 0; i < 4; i++) {
    int r = wm * 64 + i * 16 + la;
    aoffL[i] = r * 32 + ((lg ^ ((r >> 1) & 3)) * 8);
    int rb = wn * 64 + i * 16 + la;
    boffL[i] = rb * 32 + ((lg ^ ((rb >> 1) & 3)) * 8);
  }

  f32x4 acc[4][4] = {};
  for (int kt = 0; kt < 24; kt++) {
    int k0 = kt * 32;
    GLDS16(Xb + aoff0 + k0, As + tid * 8);
    GLDS16(Xb + aoff1 + k0, As + 2048 + tid * 8);
    GLDS16(Wb + boff0 + k0, Bs + tid * 8);
    GLDS16(Wb + boff1 + k0, Bs + 2048 + tid * 8);
    __syncthreads();
    bf16x8 af[4], bfv[4];
#pragma unroll
    for (int i = 0; i < 4; i++) af[i] = *(const bf16x8*)(As + aoffL[i]);
#pragma unroll
    for (int j = 0; j < 4; j++) bfv[j] = *(const bf16x8*)(Bs + boffL[j]);
#pragma unroll
    for (int i = 0; i < 4; i++)
#pragma unroll
      for (int j = 0; j < 4; j++)
        acc[i][j] = MFMA(af[i], bfv[j], acc[i][j]);
    __syncthreads();
  }

  // epilogue: bias add, bf16 convert, write Q/K row-major, V transposed [b,h,d,s]
  const float* bias = (w == 0) ? bq : ((w == 1) ? bk : bv);
#pragma unroll
  for (int j = 0; j < 4; j++) {
    int nc = n0 + wn * 64 + j * 16 + la;  // 0..767
    float bb = bias[nc];
#pragma unroll
    for (int i = 0; i < 4; i++) {
      int mrow0 = m0 + wm * 64 + i * 16 + lg * 4;
      f32x4 v = acc[i][j];
      if (w < 2) {
        __bf16* dst = (w == 0 ? Qb : Kb);
#pragma unroll
        for (int reg = 0; reg < 4; reg++)
          dst[(long)(mrow0 + reg) * HID + nc] = (__bf16)(v[reg] + bb);
      } else {
        int bI = mrow0 >> 11, s = mrow0 & 2047;
        int hh = nc >> 6, d = nc & 63;
        bf16x4 pv;
#pragma unroll
        for (int reg = 0; reg < 4; reg++) pv[reg] = (__bf16)(v[reg] + bb);
        *(bf16x4*)(Vt + ((long)(bI * NH + hh) * HD + d) * SEQ + s) = pv;
      }
    }
  }
}

// ---------------------------------------------------------------- attention
// 1 block = 64 q-rows (4 waves x 16), KV tiles of 64, flash-style online softmax.
// log2-domain softmax, defer-max (THR=8, m init 0), rowsum via MFMA-ones,
// 2-phase double-buffered K/V staging (prefetch next tile before compute).
// K/V tiles: [64 rows][64 elems] bf16, chunk-swizzle slot = c ^ (r&7).
__global__ __launch_bounds__(256) void attn_kernel(
    const __bf16* __restrict__ Qb, const __bf16* __restrict__ Kb,
    const __bf16* __restrict__ Vt, const float* __restrict__ mask,
    float* __restrict__ out) {
  __shared__ alignas(16) __bf16 Ks[2][4096];
  __shared__ alignas(16) __bf16 Vs[2][4096];
  __shared__ alignas(16) __bf16 Ps[4096];  // 4 waves x [16 q][64 k]
  int tid = threadIdx.x, lane = tid & 63, wid = tid >> 6;
  int qt = blockIdx.x, h = blockIdx.y, b = blockIdx.z;
  int la = lane & 15, lg = lane >> 4;

  // Q fragments in registers (A-frag: row = lane&15, k = (lane>>4)*8+i)
  int qrow = qt * 64 + wid * 16 + la;
  const __bf16* qp = Qb + (long)(b * SEQ + qrow) * HID + h * HD + lg * 8;
  bf16x8 qa0 = *(const bf16x8*)qp;
  bf16x8 qa1 = *(const bf16x8*)(qp + 32);

  // staging maps (source pre-swizzled, LDS dest linear)
  int r0 = tid >> 3, cc = (tid & 7) ^ (r0 & 7);
  long kbase = (long)(b * SEQ + r0) * HID + h * HD + cc * 8;
  long vbase = (long)((b * NH + h) * HD + r0) * SEQ + cc * 8;

  // fragment read offsets into Ks/Vs (same formula both)
  int koffL[4][2];
#pragma unroll
  for (int j = 0; j < 4; j++) {
    int r = j * 16 + la;
    koffL[j][0] = r * 64 + (((0 + lg) ^ (r & 7)) * 8);
    koffL[j][1] = r * 64 + (((4 + lg) ^ (r & 7)) * 8);
  }
  int poff0 = wid * 1024 + la * 64 + (((0 + lg) ^ (la & 7)) * 8);
  int poff1 = wid * 1024 + la * 64 + (((4 + lg) ^ (la & 7)) * 8);

  const float C = 0.18033688011112042f;  // 0.125 * log2(e)
  float m_run[4] = {0.f, 0.f, 0.f, 0.f}; // log2-domain running max (defer)
  float l_run[4] = {0.f, 0.f, 0.f, 0.f};
  f32x4 acc[4] = {};
  bf16x8 vone;
#pragma unroll
  for (int i = 0; i < 8; i++) vone[i] = (__bf16)1.0f;
  const float* mrow = mask + b * SEQ;

  // prologue: stage tile 0 into buffer 0
  GLDS16(Kb + kbase, &Ks[0][tid * 8]);
  GLDS16(Kb + kbase + 32L * HID, &Ks[0][2048 + tid * 8]);
  GLDS16(Vt + vbase, &Vs[0][tid * 8]);
  GLDS16(Vt + vbase + 32L * SEQ, &Vs[0][2048 + tid * 8]);
  __syncthreads();

  for (int t = 0; t < 32; t++) {
    int cur = t & 1, nxt = cur ^ 1;
    int tn = (t + 1) & 31;  // wrap at end: harmless re-stage of tile 0
    GLDS16(Kb + kbase + (long)tn * 64 * HID, &Ks[nxt][tid * 8]);
    GLDS16(Kb + kbase + (long)tn * 64 * HID + 32L * HID, &Ks[nxt][2048 + tid * 8]);
    GLDS16(Vt + vbase + tn * 64, &Vs[nxt][tid * 8]);
    GLDS16(Vt + vbase + tn * 64 + 32L * SEQ, &Vs[nxt][2048 + tid * 8]);

    // S = Q K^T  (rows: lane holds rows lg*4+r, col = j*16+la)
    f32x4 s[4];
#pragma unroll
    for (int j = 0; j < 4; j++) {
      bf16x8 k0 = *(const bf16x8*)(&Ks[cur][0] + koffL[j][0]);
      bf16x8 k1 = *(const bf16x8*)(&Ks[cur][0] + koffL[j][1]);
      f32x4 z = {};
      z = MFMA(qa0, k0, z);
      z = MFMA(qa1, k1, z);
      s[j] = z;
    }

    // log2-domain: arg = s*0.125*log2e + (mneg - m_run); per-lane max check
    float mx[4] = {-1e30f, -1e30f, -1e30f, -1e30f};
#pragma unroll
    for (int j = 0; j < 4; j++) {
      float mv = mrow[t * 64 + j * 16 + la];
      float mneg = (mv < 0.0f) ? -30000.0f : 0.0f;
#pragma unroll
      for (int r = 0; r < 4; r++) {
        float a = fmaf(s[j][r], C, mneg - m_run[r]);
        s[j][r] = a;
        mx[r] = fmaxf(mx[r], a);
      }
    }
    int ok = (mx[0] <= 8.f) & (mx[1] <= 8.f) & (mx[2] <= 8.f) & (mx[3] <= 8.f);
    if (__builtin_expect(!__all(ok), 0)) {
      // rare: true row-max reduce + rescale
#pragma unroll
      for (int r = 0; r < 4; r++) {
        float rm = mx[r];
#pragma unroll
        for (int o = 1; o < 16; o <<= 1) rm = fmaxf(rm, __shfl_xor(rm, o, 16));
        rm = fmaxf(rm, 0.0f);
        float corr = __builtin_amdgcn_exp2f(-rm);
        m_run[r] += rm;
        l_run[r] *= corr;
#pragma unroll
        for (int jo = 0; jo < 4; jo++) acc[jo][r] *= corr;
#pragma unroll
        for (int j = 0; j < 4; j++) s[j][r] -= rm;
      }
    }

    // P = exp2(arg) -> bf16 -> per-wave LDS (swizzled) transpose to A-frag
#pragma unroll
    for (int j = 0; j < 4; j++)
#pragma unroll
      for (int r = 0; r < 4; r++) {
        float p = __builtin_amdgcn_exp2f(s[j][r]);
        int row = lg * 4 + r, col = j * 16 + la;
        Ps[wid * 1024 + row * 64 + (((col >> 3) ^ (row & 7)) * 8) + (col & 7)] =
            (__bf16)p;
      }
    bf16x8 pa0 = *(const bf16x8*)(Ps + poff0);
    bf16x8 pa1 = *(const bf16x8*)(Ps + poff1);

    // l += rowsum(P) via MFMA with ones-B (D layout matches l_run slots)
    f32x4 z = {};
    z = MFMA(pa0, vone, z);
    z = MFMA(pa1, vone, z);
#pragma unroll
    for (int r = 0; r < 4; r++) l_run[r] += z[r];

    // O += P V   (B-frag from Vt rows: B[k=s][col=d])
#pragma unroll
    for (int jo = 0; jo < 4; jo++) {
      bf16x8 v0 = *(const bf16x8*)(&Vs[cur][0] + koffL[jo][0]);
      bf16x8 v1 = *(const bf16x8*)(&Vs[cur][0] + koffL[jo][1]);
      acc[jo] = MFMA(pa0, v0, acc[jo]);
      acc[jo] = MFMA(pa1, v1, acc[jo]);
    }
    __syncthreads();  // drains vmcnt -> next buffer ready; all done with cur
  }

  // epilogue: out[b, s, h*64+d] = acc / l
#pragma unroll
  for (int jo = 0; jo < 4; jo++)
#pragma unroll
    for (int r = 0; r < 4; r++) {
      int row = qt * 64 + wid * 16 + lg * 4 + r;
      int d = jo * 16 + la;
      out[(long)(b * SEQ + row) * HID + h * HD + d] = acc[jo][r] / l_run[r];
    }
}

// ---------------------------------------------------------------- launch
extern "C" void kernel_launch(void* const* d_in, const int* in_sizes, int n_in,
                              void* d_out, int out_size, void* d_ws, size_t ws_size,
                              hipStream_t stream) {
  const float* X    = (const float*)d_in[0];
  const float* mask = (const float*)d_in[1];
  const float* Wq   = (const float*)d_in[2];
  const float* bq   = (const float*)d_in[3];
  const float* Wk   = (const float*)d_in[4];
  const float* bk   = (const float*)d_in[5];
  const float* Wv   = (const float*)d_in[6];
  const float* bv   = (const float*)d_in[7];

  __bf16* Xb = (__bf16*)d_ws;            // 6291456
  __bf16* Wb = Xb + 6291456;             // 1769472 (Wq,Wk,Wv)
  __bf16* Qb = Wb + 1769472;             // 6291456
  __bf16* Kb = Qb + 6291456;             // 6291456
  __bf16* Vt = Kb + 6291456;             // 6291456, layout [b][h][d][s]
  float* out = (float*)d_out;

  cvt_kernel<<<dim3(3936), dim3(256), 0, stream>>>(X, Wq, Wk, Wv, Xb, Wb);
  qkv_kernel<<<dim3(1152), dim3(256), 0, stream>>>(Xb, Wb, bq, bk, bv, Qb, Kb, Vt);
  attn_kernel<<<dim3(32, 12, 4), dim3(256), 0, stream>>>(Qb, Kb, Vt, mask, out);
}